// Round 11
// baseline (982.917 us; speedup 1.0000x reference)
//
#include <hip/hip_runtime.h>

// Problem constants (from reference)
#define NODES  50000
#define EDGES  800000
#define NGRAPH 512

// short-element offsets inside the canonical bf16 weight buffer (wbuf).
// All W matrices are stored TRANSPOSED: Wt[j][k] (128 rows x CH cols), so the
// MFMA B-fragment (8 consecutive k for fixed j) is a contiguous 16B load.
#define OFF_WL0T 0         // [128][64]
#define OFF_WR0T 8192      // [128][64]
#define OFF_WLT  16384     // 11 x [128][128]
#define OFF_WRT  196608    // 11 x [128][128]
#define OFF_B0   376832    // 128
#define OFF_B    376960    // 11*128
#define OFF_HW   378368    // 128*2 (row-major, as input)
#define OFF_HB   378624    // 2
#define WBUF_N   378626

typedef __attribute__((ext_vector_type(8))) short bf16x8;
typedef __attribute__((ext_vector_type(4))) float f32x4;

// ---------- bf16 helpers (internal compute fp32) ----------
__device__ __forceinline__ float bflo(unsigned int u) {
    union { unsigned int i; float f; } c; c.i = u << 16; return c.f;
}
__device__ __forceinline__ float bfhi(unsigned int u) {
    union { unsigned int i; float f; } c; c.i = u & 0xffff0000u; return c.f;
}
__device__ __forceinline__ float bf2f(unsigned short u) {
    union { unsigned int i; float f; } c; c.i = ((unsigned int)u) << 16; return c.f;
}
__device__ __forceinline__ unsigned short f2bf(float f) {
    union { float f; unsigned int i; } c; c.f = f;
    unsigned int u = c.i;
    u = (u + 0x7fffu + ((u >> 16) & 1u)) >> 16;   // round-to-nearest-even
    return (unsigned short)u;
}

// ---------- block-local dtype sniff: bf16 inputs -> 0, fp32 inputs -> 1 ----------
// 64-lane shuffle reduction: MUST be called by ALL lanes of a wave, i.e. before
// any divergent early-return (round-10 bug: tail-wave lanes exited first ->
// undefined shuffle -> mode garbage -> OOB fp32 reads of the head weights).
__device__ __forceinline__ int detect_mode(const unsigned int* __restrict__ xu) {
    int bad = 0;
    for (int i = (threadIdx.x & 63); i < 512; i += 64) {
        const unsigned int u = xu[i];
        if (!(fabsf(bflo(u)) < 1e4f)) bad++;   // also catches NaN
        if (!(fabsf(bfhi(u)) < 1e4f)) bad++;
    }
#pragma unroll
    for (int off = 32; off; off >>= 1) bad += __shfl_down(bad, off);
    bad = __shfl(bad, 0);
    return (bad > 16) ? 1 : 0;
}

// ---------- repack weights into canonical bf16 buffer (W's transposed) ----------
__global__ __launch_bounds__(256) void k_cvt_w(const void* xin,
                                               const void* s0, const void* s1, const void* s2,
                                               const void* s3, const void* s4, const void* s5,
                                               const void* s6, const void* s7,
                                               unsigned short* __restrict__ wbuf) {
    const int m = detect_mode((const unsigned int*)xin);   // before any divergent return
    const int i = blockIdx.x * 256 + threadIdx.x;
    if (i >= WBUF_N) return;
    const void* src; int local;
    if (i < OFF_WR0T) {                       // Wl0^T: out(j,k) <- in(k,j), in = 64x128
        const int j = i >> 6, k = i & 63;
        src = s0; local = k * 128 + j;
    } else if (i < OFF_WLT) {                 // Wr0^T
        const int t = i - OFF_WR0T, j = t >> 6, k = t & 63;
        src = s1; local = k * 128 + j;
    } else if (i < OFF_WRT) {                 // Wl^T: 11 x (out(j,k) <- in(k,j)), in = 128x128
        const int t = i - OFF_WLT, l = t >> 14, r = t & 16383, j = r >> 7, k = r & 127;
        src = s3; local = (l << 14) + k * 128 + j;
    } else if (i < OFF_B0) {                  // Wr^T
        const int t = i - OFF_WRT, l = t >> 14, r = t & 16383, j = r >> 7, k = r & 127;
        src = s4; local = (l << 14) + k * 128 + j;
    } else if (i < OFF_B) {
        src = s2; local = i - OFF_B0;         // b0
    } else if (i < OFF_HW) {
        src = s5; local = i - OFF_B;          // b
    } else if (i < OFF_HB) {
        src = s6; local = i - OFF_HW;         // head_W
    } else {
        src = s7; local = i - OFF_HB;         // head_b
    }
    wbuf[i] = m ? f2bf(((const float*)src)[local]) : ((const unsigned short*)src)[local];
}

// ---------- x -> canonical bf16 (N x 64) + zero deg/gsum/gcnt in tail blocks ----------
#define CVT_BLOCKS 1563    // ceil(NODES*64/8 / 256)
#define ZERO_WORDS (NODES + NGRAPH * 128 + NGRAPH)   // deg + gsum + gcnt
__global__ __launch_bounds__(256) void k_cvt_x(const void* __restrict__ xin,
                                               unsigned short* __restrict__ hx,
                                               int* __restrict__ deg,
                                               float* __restrict__ gsum,
                                               float* __restrict__ gcnt) {
    if (blockIdx.x >= CVT_BLOCKS) {           // zeroing tail (block-uniform branch)
        const int i = (blockIdx.x - CVT_BLOCKS) * 256 + threadIdx.x;
        if (i < NODES) deg[i] = 0;
        else if (i < NODES + NGRAPH * 128) gsum[i - NODES] = 0.f;
        else if (i < ZERO_WORDS) gcnt[i - NODES - NGRAPH * 128] = 0.f;
        return;
    }
    const int m = detect_mode((const unsigned int*)xin);   // before divergent return
    const int i = blockIdx.x * 256 + threadIdx.x;   // groups of 8 elements
    if (i >= NODES * 64 / 8) return;
    if (m == 0) {
        ((uint4*)hx)[i] = ((const uint4*)xin)[i];
    } else {
        const float4* f = (const float4*)xin;
        const float4 a = f[2 * i], b = f[2 * i + 1];
        const unsigned int p0 = f2bf(a.x) | ((unsigned int)f2bf(a.y) << 16);
        const unsigned int p1 = f2bf(a.z) | ((unsigned int)f2bf(a.w) << 16);
        const unsigned int p2 = f2bf(b.x) | ((unsigned int)f2bf(b.y) << 16);
        const unsigned int p3 = f2bf(b.z) | ((unsigned int)f2bf(b.w) << 16);
        ((uint4*)hx)[i] = make_uint4(p0, p1, p2, p3);
    }
}

// ---------- CSR build (by dst) ----------
__global__ __launch_bounds__(256) void k_count(const int* __restrict__ ei,
                                               int* __restrict__ deg) {
    const int e = blockIdx.x * 256 + threadIdx.x;
    if (e < EDGES) {
        const int d = ei[EDGES + e];
        if ((unsigned)d < NODES) atomicAdd(&deg[d], 1);
    }
}

__global__ __launch_bounds__(1024) void k_scan_block(const int* __restrict__ deg,
                                                     int* __restrict__ tmp,
                                                     int* __restrict__ bsums) {
    __shared__ int s[1024];
    const int idx = blockIdx.x * 1024 + threadIdx.x;
    s[threadIdx.x] = (idx < NODES) ? deg[idx] : 0;
    __syncthreads();
    for (int off = 1; off < 1024; off <<= 1) {
        int v = (threadIdx.x >= off) ? s[threadIdx.x - off] : 0;
        __syncthreads();
        s[threadIdx.x] += v;
        __syncthreads();
    }
    if (idx < NODES) tmp[idx] = s[threadIdx.x];
    if (threadIdx.x == 1023) bsums[blockIdx.x] = s[1023];
}

__global__ void k_scan_sums(int* __restrict__ bsums, int nb) {
    if (threadIdx.x == 0 && blockIdx.x == 0) {
        int acc = 0;
        for (int i = 0; i < nb; ++i) { int v = bsums[i]; bsums[i] = acc; acc += v; }
    }
}

__global__ __launch_bounds__(1024) void k_scan_fin(const int* __restrict__ deg,
                                                   const int* __restrict__ tmp,
                                                   const int* __restrict__ bsums,
                                                   int* __restrict__ row_ptr,
                                                   int* __restrict__ cursor,
                                                   float* __restrict__ inv_deg) {
    const int idx = blockIdx.x * 1024 + threadIdx.x;
    if (idx >= NODES) return;
    const int incl = tmp[idx] + bsums[blockIdx.x];
    const int d = deg[idx];
    row_ptr[idx + 1] = incl;
    cursor[idx] = incl - d;
    inv_deg[idx] = (d > 0) ? (1.0f / (float)d) : 0.0f;
    if (idx == 0) row_ptr[0] = 0;
}

// csr_src store is an atomicExch: atomics execute at the coherent point (MALL),
// so random 4B scatters coalesce there instead of leaving partial dirty lines
// in 8 incoherent per-XCD L2s (round-9 k_fill: WRITE_SIZE 52 MB for 3.2 MB data).
__global__ __launch_bounds__(256) void k_fill(const int* __restrict__ ei,
                                              int* __restrict__ cursor,
                                              int* __restrict__ csr_src) {
    const int e = blockIdx.x * 256 + threadIdx.x;
    if (e < EDGES) {
        const int d = ei[EDGES + e];
        if ((unsigned)d < NODES) {
            const int p = atomicAdd(&cursor[d], 1);
            atomicExch(&csr_src[p], ei[e]);
        }
    }
}

// ws-too-small sentinel: absmax will read ~(1000 + ws_MB)
__global__ __launch_bounds__(256) void k_ws_stamp(unsigned short* __restrict__ outp, float v) {
    const int t = blockIdx.x * 256 + threadIdx.x;
    if (t < NGRAPH * 2) outp[t] = f2bf(v);
}

// ---------- mean aggregation: lane = 8 B (uint2); 16-deep gather batches ----------
// Indices prefetched to registers, then 16 uint2 loads issued back-to-back:
// 8 KB outstanding/wave. Writes bf16 agg at FIXED stride 128 shorts into `agg`
// (may alias the next GEMM's output buffer).
template <int CH>
__global__ __launch_bounds__(256) void k_agg(const unsigned short* __restrict__ h,   // N x CH
                                             const int* __restrict__ row_ptr,
                                             const int* __restrict__ csr_src,
                                             const float* __restrict__ inv_deg,
                                             unsigned short* __restrict__ agg) {     // N x 128
    constexpr int LPN = CH / 4;                 // uint2 lanes per node (32 or 16)
    constexpr int NPW = 64 / LPN;               // nodes per wave (2 or 4)
    const int wave = threadIdx.x >> 6;
    const int lane = threadIdx.x & 63;
    const int sub = lane / LPN;
    const int cl = lane & (LPN - 1);
    const int node = (blockIdx.x * 4 + wave) * NPW + sub;
    if (node >= NODES) return;
    const int e1 = row_ptr[node + 1];
    const uint2* hb = (const uint2*)h;
    float c0 = 0.f, c1 = 0.f, c2 = 0.f, c3 = 0.f;
    int e = row_ptr[node];
    for (; e + 15 < e1; e += 16) {
        int idx[16];
#pragma unroll
        for (int j = 0; j < 16; ++j) idx[j] = csr_src[e + j];
        uint2 u[16];
#pragma unroll
        for (int j = 0; j < 16; ++j) u[j] = hb[(size_t)idx[j] * LPN + cl];
#pragma unroll
        for (int j = 0; j < 16; ++j) {
            c0 += bflo(u[j].x); c1 += bfhi(u[j].x);
            c2 += bflo(u[j].y); c3 += bfhi(u[j].y);
        }
    }
    for (; e + 7 < e1; e += 8) {
        uint2 u[8];
#pragma unroll
        for (int j = 0; j < 8; ++j)
            u[j] = hb[(size_t)csr_src[e + j] * LPN + cl];
#pragma unroll
        for (int j = 0; j < 8; ++j) {
            c0 += bflo(u[j].x); c1 += bfhi(u[j].x);
            c2 += bflo(u[j].y); c3 += bfhi(u[j].y);
        }
    }
    for (; e < e1; ++e) {
        const uint2 u = hb[(size_t)csr_src[e] * LPN + cl];
        c0 += bflo(u.x); c1 += bfhi(u.x);
        c2 += bflo(u.y); c3 += bfhi(u.y);
    }
    const float inv = inv_deg[node];
    uint2 o;
    o.x = f2bf(c0 * inv) | ((unsigned int)f2bf(c1 * inv) << 16);
    o.y = f2bf(c2 * inv) | ((unsigned int)f2bf(c3 * inv) << 16);
    ((uint2*)agg)[(size_t)node * 32 + cl] = o;
}

// ---------- MFMA SAGE GEMM: out = act(agg @ Wl + h @ Wr + b) ----------
// Block = 256 thr (4 waves), tile 64 rows x 128 cols. Wave w: rows
// m0 = blk*64 + (w&1)*32 (2 m-tiles), cols n0 = (w>>1)*64 (4 n-tiles) ->
// 8 MFMAs/step, B-frag reused 2x. Register double-buffer on A and B.
// Unified K-loop: steps 0..KC-1 = agg@Wl, KC..2KC-1 = h@Wr.
// mfma_f32_16x16x32_bf16 layouts (m89/m120-verified):
//   A-frag: lane holds A[m=lane&15][k=quad*8+j]; B-frag: B[k=quad*8+j][n=lane&15]
//   C/D: lane reg r holds D[row=quad*4+r][col=lane&15]
// agg stride 128; h stride CH. A reads and D writes cover the same rows, so agg
// may live in the output buffer. act: 0=none 1=relu 2=leaky(0.01)
template <int CH>
__global__ __launch_bounds__(256) void k_gemm(const unsigned short* __restrict__ agg, // N x 128
                                              const unsigned short* __restrict__ h,   // N x CH
                                              const unsigned short* __restrict__ Wt1, // [128][CH]
                                              const unsigned short* __restrict__ Wt2, // [128][CH]
                                              const unsigned short* __restrict__ bias,
                                              unsigned short* __restrict__ outp,      // N x 128
                                              int act) {
    const int wave = threadIdx.x >> 6;
    const int lane = threadIdx.x & 63;
    const int quad = lane >> 4;
    const int l16 = lane & 15;
    const int m0 = blockIdx.x * 64 + (wave & 1) * 32;
    const int n0 = (wave >> 1) * 64;
    int rowA0 = m0 + l16;
    int rowA1 = m0 + 16 + l16;
    if (rowA0 >= NODES) rowA0 = NODES - 1;   // clamped rows feed MFMA, never stored
    if (rowA1 >= NODES) rowA1 = NODES - 1;

    constexpr int KC = CH / 32;
    constexpr int NS = 2 * KC;

    auto loadA = [&](int s, int row) -> bf16x8 {
        const int half = (s >= KC) ? 1 : 0;
        const int kc = s - half * KC;
        const unsigned short* base = half ? h : agg;
        const int stride = half ? CH : 128;
        return *(const bf16x8*)(base + (size_t)row * stride + kc * 32 + quad * 8);
    };
    auto loadB = [&](int s, int nt) -> bf16x8 {
        const int half = (s >= KC) ? 1 : 0;
        const int kc = s - half * KC;
        const unsigned short* W = half ? Wt2 : Wt1;
        return *(const bf16x8*)(W + (size_t)(n0 + nt * 16 + l16) * CH + kc * 32 + quad * 8);
    };

    f32x4 acc[2][4] = {};
    bf16x8 a0 = loadA(0, rowA0);
    bf16x8 a1 = loadA(0, rowA1);
    bf16x8 b[4];
#pragma unroll
    for (int nt = 0; nt < 4; ++nt) b[nt] = loadB(0, nt);

#pragma unroll
    for (int s = 0; s < NS; ++s) {
        bf16x8 na0, na1, nb[4];
        if (s + 1 < NS) {                      // issue next step's loads first
            na0 = loadA(s + 1, rowA0);
            na1 = loadA(s + 1, rowA1);
#pragma unroll
            for (int nt = 0; nt < 4; ++nt) nb[nt] = loadB(s + 1, nt);
        }
#pragma unroll
        for (int nt = 0; nt < 4; ++nt) {
            acc[0][nt] = __builtin_amdgcn_mfma_f32_16x16x32_bf16(a0, b[nt], acc[0][nt], 0, 0, 0);
            acc[1][nt] = __builtin_amdgcn_mfma_f32_16x16x32_bf16(a1, b[nt], acc[1][nt], 0, 0, 0);
        }
        if (s + 1 < NS) {
            a0 = na0; a1 = na1;
#pragma unroll
            for (int nt = 0; nt < 4; ++nt) b[nt] = nb[nt];
        }
    }

#pragma unroll
    for (int nt = 0; nt < 4; ++nt) {
        const float bj = bf2f(bias[n0 + nt * 16 + l16]);
#pragma unroll
        for (int mt = 0; mt < 2; ++mt) {
#pragma unroll
            for (int r = 0; r < 4; ++r) {
                const int row = m0 + mt * 16 + quad * 4 + r;
                if (row < NODES) {
                    float v = acc[mt][nt][r] + bj;
                    if (act == 1) v = fmaxf(v, 0.f);
                    else if (act == 2) v = v > 0.f ? v : 0.01f * v;
                    outp[(size_t)row * 128 + n0 + nt * 16 + l16] = f2bf(v);
                }
            }
        }
    }
}

// ---------- segmented global mean pool (batch_idx sorted) ----------
// 512 threads = 4 substreams x 128 channels; block covers 128 nodes; substream
// sg scans nodes n0+4i+sg (sorted within stream), flushing at graph transitions.
__global__ __launch_bounds__(512) void k_pool(const unsigned short* __restrict__ h,
                                              const int* __restrict__ batch,
                                              float* __restrict__ gsum,
                                              float* __restrict__ gcnt) {
    const int c = threadIdx.x & 127;
    const int sg = threadIdx.x >> 7;            // 0..3
    const int n0 = blockIdx.x * 128;
    float s = 0.f;
    int cnt = 0, gprev = -1;
#pragma unroll 4
    for (int i = 0; i < 32; ++i) {
        const int n = n0 + i * 4 + sg;
        if (n >= NODES) break;
        int g = batch[n];
        if ((unsigned)g >= NGRAPH) g = (gprev < 0) ? 0 : gprev;
        if (g != gprev) {
            if (gprev >= 0) {
                atomicAdd(&gsum[(size_t)gprev * 128 + c], s);
                if (c == 0) atomicAdd(&gcnt[gprev], (float)cnt);
            }
            s = 0.f; cnt = 0; gprev = g;
        }
        s += bf2f(h[(size_t)n * 128 + c]);
        cnt++;
    }
    if (gprev >= 0) {
        atomicAdd(&gsum[(size_t)gprev * 128 + c], s);
        if (c == 0) atomicAdd(&gcnt[gprev], (float)cnt);
    }
}

// ---------- head: out = pooled @ head_W + head_b (dtype-adaptive store) ----------
__global__ __launch_bounds__(256) void k_head(const float* __restrict__ gsum,
                                              const float* __restrict__ gcnt,
                                              const unsigned short* __restrict__ wbuf,
                                              const void* __restrict__ xin,
                                              void* __restrict__ outp) {
    const int m = detect_mode((const unsigned int*)xin);   // before any divergent return
    const int t = blockIdx.x * 256 + threadIdx.x;
    if (t >= NGRAPH * 2) return;
    const int g = t >> 1, o = t & 1;
    const float inv = 1.0f / fmaxf(gcnt[g], 1.0f);
    float s = bf2f(wbuf[OFF_HB + o]);
    for (int c = 0; c < 128; ++c)
        s += gsum[(size_t)g * 128 + c] * inv * bf2f(wbuf[OFF_HW + c * 2 + o]);
    if (m) ((float*)outp)[t] = s;
    else ((unsigned short*)outp)[t] = f2bf(s);
}

extern "C" void kernel_launch(void* const* d_in, const int* in_sizes, int n_in,
                              void* d_out, int out_size, void* d_ws, size_t ws_size,
                              hipStream_t stream) {
    const void* x     = d_in[0];
    const int*  ei    = (const int*)d_in[1];
    const int*  batch = (const int*)d_in[2];

    // ---- workspace carve-up (~30.8 MB; ws_size measured 256 MB in round 8) ----
    char* p = (char*)d_ws;
    auto alloc = [&](size_t bytes) -> void* {
        void* r = (void*)p;
        p += (bytes + 255) & ~(size_t)255;
        return r;
    };
    unsigned short* hA   = (unsigned short*)alloc((size_t)NODES * 128 * 2);  // holds x (N x 64) first
    unsigned short* hB   = (unsigned short*)alloc((size_t)NODES * 128 * 2);
    unsigned short* wbuf = (unsigned short*)alloc((size_t)(WBUF_N + 14) * 2);
    int*   deg     = (int*)alloc((size_t)NODES * 4);
    int*   tmp     = (int*)alloc((size_t)NODES * 4);
    int*   row_ptr = (int*)alloc((size_t)(NODES + 1) * 4);
    int*   cursor  = (int*)alloc((size_t)NODES * 4);
    float* inv_deg = (float*)alloc((size_t)NODES * 4);
    int*   csr_src = (int*)alloc((size_t)EDGES * 4);
    int*   bsums   = (int*)alloc(64 * 4);
    float* gsum    = (float*)alloc((size_t)NGRAPH * 128 * 4);
    float* gcnt    = (float*)alloc((size_t)NGRAPH * 4);
    const size_t need = (size_t)(p - (char*)d_ws);
    (void)in_sizes; (void)n_in; (void)out_size;

    if (ws_size < need) {
        k_ws_stamp<<<4, 256, 0, stream>>>((unsigned short*)d_out,
                                          1000.0f + (float)(ws_size >> 20));
        return;
    }

    // setup: weight repack (mode sniffed block-locally), x convert + zero tail
    const int zeroBlocks = (ZERO_WORDS + 255) / 256;
    k_cvt_w<<<(WBUF_N + 255) / 256, 256, 0, stream>>>(x, d_in[3], d_in[4], d_in[5], d_in[6],
                                                      d_in[7], d_in[8], d_in[9], d_in[10], wbuf);
    k_cvt_x<<<CVT_BLOCKS + zeroBlocks, 256, 0, stream>>>(x, hA, deg, gsum, gcnt);

    // CSR build (by dst)
    const int nbScan = (NODES + 1023) / 1024;   // 49
    k_count<<<(EDGES + 255) / 256, 256, 0, stream>>>(ei, deg);
    k_scan_block<<<nbScan, 1024, 0, stream>>>(deg, tmp, bsums);
    k_scan_sums<<<1, 64, 0, stream>>>(bsums, nbScan);
    k_scan_fin<<<nbScan, 1024, 0, stream>>>(deg, tmp, bsums, row_ptr, cursor, inv_deg);
    k_fill<<<(EDGES + 255) / 256, 256, 0, stream>>>(ei, cursor, csr_src);

    const int gemmGrid = (NODES + 63) / 64;      // 782 (64 rows per block)

    // conv 0: 64 -> 128, ReLU. x in hA (N x 64); agg staged in hB (stride 128);
    // GEMM reads agg only from rows it itself overwrites -> no extra buffer.
    k_agg<64><<<(NODES + 15) / 16, 256, 0, stream>>>(hA, row_ptr, csr_src, inv_deg, hB);
    k_gemm<64><<<gemmGrid, 256, 0, stream>>>(hB, hA, wbuf + OFF_WL0T, wbuf + OFF_WR0T,
                                             wbuf + OFF_B0, hB, 1);

    // convs 1..11: 128 -> 128, ping-pong hB <-> hA (agg staged in nxt)
    unsigned short* cur = hB;
    unsigned short* nxt = hA;
    for (int i = 0; i < 11; ++i) {
        const int ci = i + 1;
        const int act = ((ci + 1) % 4 != 0) ? 1 : ((ci == 3 || ci == 7) ? 2 : 0);
        k_agg<128><<<(NODES + 7) / 8, 256, 0, stream>>>(cur, row_ptr, csr_src, inv_deg, nxt);
        k_gemm<128><<<gemmGrid, 256, 0, stream>>>(nxt, cur,
                                                  wbuf + OFF_WLT + (size_t)i * 128 * 128,
                                                  wbuf + OFF_WRT + (size_t)i * 128 * 128,
                                                  wbuf + OFF_B + (size_t)i * 128,
                                                  nxt, act);
        unsigned short* t = cur; cur = nxt; nxt = t;
    }

    // pool + head
    k_pool<<<(NODES + 127) / 128, 512, 0, stream>>>(cur, batch, gsum, gcnt);
    k_head<<<(NGRAPH * 2 + 255) / 256, 256, 0, stream>>>(gsum, gcnt, wbuf, x, d_out);
}

// Round 12
// 894.321 us; speedup vs baseline: 1.0991x; 1.0991x over previous
//
#include <hip/hip_runtime.h>

// Problem constants (from reference)
#define NODES  50000
#define EDGES  800000
#define NGRAPH 512

// short-element offsets inside the canonical bf16 weight buffer (wbuf).
// All W matrices are stored TRANSPOSED: Wt[j][k] (128 rows x CH cols), so the
// MFMA B-fragment (8 consecutive k for fixed j) is a contiguous 16B load.
#define OFF_WL0T 0         // [128][64]
#define OFF_WR0T 8192      // [128][64]
#define OFF_WLT  16384     // 11 x [128][128]
#define OFF_WRT  196608    // 11 x [128][128]
#define OFF_B0   376832    // 128
#define OFF_B    376960    // 11*128
#define OFF_HW   378368    // 128*2 (row-major, as input)
#define OFF_HB   378624    // 2
#define WBUF_N   378626

typedef __attribute__((ext_vector_type(8))) short bf16x8;
typedef __attribute__((ext_vector_type(4))) float f32x4;

// ---------- bf16 helpers (internal compute fp32) ----------
__device__ __forceinline__ float bflo(unsigned int u) {
    union { unsigned int i; float f; } c; c.i = u << 16; return c.f;
}
__device__ __forceinline__ float bfhi(unsigned int u) {
    union { unsigned int i; float f; } c; c.i = u & 0xffff0000u; return c.f;
}
__device__ __forceinline__ float bf2f(unsigned short u) {
    union { unsigned int i; float f; } c; c.i = ((unsigned int)u) << 16; return c.f;
}
__device__ __forceinline__ unsigned short f2bf(float f) {
    union { float f; unsigned int i; } c; c.f = f;
    unsigned int u = c.i;
    u = (u + 0x7fffu + ((u >> 16) & 1u)) >> 16;   // round-to-nearest-even
    return (unsigned short)u;
}

// ---------- block-local dtype sniff: bf16 inputs -> 0, fp32 inputs -> 1 ----------
// 64-lane shuffle reduction: MUST be called by ALL lanes of a wave, i.e. before
// any divergent early-return (round-10 bug).
__device__ __forceinline__ int detect_mode(const unsigned int* __restrict__ xu) {
    int bad = 0;
    for (int i = (threadIdx.x & 63); i < 512; i += 64) {
        const unsigned int u = xu[i];
        if (!(fabsf(bflo(u)) < 1e4f)) bad++;   // also catches NaN
        if (!(fabsf(bfhi(u)) < 1e4f)) bad++;
    }
#pragma unroll
    for (int off = 32; off; off >>= 1) bad += __shfl_down(bad, off);
    bad = __shfl(bad, 0);
    return (bad > 16) ? 1 : 0;
}

// ---------- repack weights into canonical bf16 buffer (W's transposed) ----------
__global__ __launch_bounds__(256) void k_cvt_w(const void* xin,
                                               const void* s0, const void* s1, const void* s2,
                                               const void* s3, const void* s4, const void* s5,
                                               const void* s6, const void* s7,
                                               unsigned short* __restrict__ wbuf) {
    const int m = detect_mode((const unsigned int*)xin);   // before any divergent return
    const int i = blockIdx.x * 256 + threadIdx.x;
    if (i >= WBUF_N) return;
    const void* src; int local;
    if (i < OFF_WR0T) {                       // Wl0^T: out(j,k) <- in(k,j), in = 64x128
        const int j = i >> 6, k = i & 63;
        src = s0; local = k * 128 + j;
    } else if (i < OFF_WLT) {                 // Wr0^T
        const int t = i - OFF_WR0T, j = t >> 6, k = t & 63;
        src = s1; local = k * 128 + j;
    } else if (i < OFF_WRT) {                 // Wl^T: 11 x (out(j,k) <- in(k,j)), in = 128x128
        const int t = i - OFF_WLT, l = t >> 14, r = t & 16383, j = r >> 7, k = r & 127;
        src = s3; local = (l << 14) + k * 128 + j;
    } else if (i < OFF_B0) {                  // Wr^T
        const int t = i - OFF_WRT, l = t >> 14, r = t & 16383, j = r >> 7, k = r & 127;
        src = s4; local = (l << 14) + k * 128 + j;
    } else if (i < OFF_B) {
        src = s2; local = i - OFF_B0;         // b0
    } else if (i < OFF_HW) {
        src = s5; local = i - OFF_B;          // b
    } else if (i < OFF_HB) {
        src = s6; local = i - OFF_HW;         // head_W
    } else {
        src = s7; local = i - OFF_HB;         // head_b
    }
    wbuf[i] = m ? f2bf(((const float*)src)[local]) : ((const unsigned short*)src)[local];
}

// ---------- x -> canonical bf16 (N x 64) + zero deg/gsum/gcnt in tail blocks ----------
#define CVT_BLOCKS 1563    // ceil(NODES*64/8 / 256)
#define ZERO_WORDS (NODES + NGRAPH * 128 + NGRAPH)   // deg + gsum + gcnt
__global__ __launch_bounds__(256) void k_cvt_x(const void* __restrict__ xin,
                                               unsigned short* __restrict__ hx,
                                               int* __restrict__ deg,
                                               float* __restrict__ gsum,
                                               float* __restrict__ gcnt) {
    if (blockIdx.x >= CVT_BLOCKS) {           // zeroing tail (block-uniform branch)
        const int i = (blockIdx.x - CVT_BLOCKS) * 256 + threadIdx.x;
        if (i < NODES) deg[i] = 0;
        else if (i < NODES + NGRAPH * 128) gsum[i - NODES] = 0.f;
        else if (i < ZERO_WORDS) gcnt[i - NODES - NGRAPH * 128] = 0.f;
        return;
    }
    const int m = detect_mode((const unsigned int*)xin);   // before divergent return
    const int i = blockIdx.x * 256 + threadIdx.x;   // groups of 8 elements
    if (i >= NODES * 64 / 8) return;
    if (m == 0) {
        ((uint4*)hx)[i] = ((const uint4*)xin)[i];
    } else {
        const float4* f = (const float4*)xin;
        const float4 a = f[2 * i], b = f[2 * i + 1];
        const unsigned int p0 = f2bf(a.x) | ((unsigned int)f2bf(a.y) << 16);
        const unsigned int p1 = f2bf(a.z) | ((unsigned int)f2bf(a.w) << 16);
        const unsigned int p2 = f2bf(b.x) | ((unsigned int)f2bf(b.y) << 16);
        const unsigned int p3 = f2bf(b.z) | ((unsigned int)f2bf(b.w) << 16);
        ((uint4*)hx)[i] = make_uint4(p0, p1, p2, p3);
    }
}

// ---------- CSR build (by dst) ----------
__global__ __launch_bounds__(256) void k_count(const int* __restrict__ ei,
                                               int* __restrict__ deg) {
    const int e = blockIdx.x * 256 + threadIdx.x;
    if (e < EDGES) {
        const int d = ei[EDGES + e];
        if ((unsigned)d < NODES) atomicAdd(&deg[d], 1);
    }
}

__global__ __launch_bounds__(1024) void k_scan_block(const int* __restrict__ deg,
                                                     int* __restrict__ tmp,
                                                     int* __restrict__ bsums) {
    __shared__ int s[1024];
    const int idx = blockIdx.x * 1024 + threadIdx.x;
    s[threadIdx.x] = (idx < NODES) ? deg[idx] : 0;
    __syncthreads();
    for (int off = 1; off < 1024; off <<= 1) {
        int v = (threadIdx.x >= off) ? s[threadIdx.x - off] : 0;
        __syncthreads();
        s[threadIdx.x] += v;
        __syncthreads();
    }
    if (idx < NODES) tmp[idx] = s[threadIdx.x];
    if (threadIdx.x == 1023) bsums[blockIdx.x] = s[1023];
}

__global__ void k_scan_sums(int* __restrict__ bsums, int nb) {
    if (threadIdx.x == 0 && blockIdx.x == 0) {
        int acc = 0;
        for (int i = 0; i < nb; ++i) { int v = bsums[i]; bsums[i] = acc; acc += v; }
    }
}

__global__ __launch_bounds__(1024) void k_scan_fin(const int* __restrict__ deg,
                                                   const int* __restrict__ tmp,
                                                   const int* __restrict__ bsums,
                                                   int* __restrict__ row_ptr,
                                                   int* __restrict__ cursor,
                                                   float* __restrict__ inv_deg) {
    const int idx = blockIdx.x * 1024 + threadIdx.x;
    if (idx >= NODES) return;
    const int incl = tmp[idx] + bsums[blockIdx.x];
    const int d = deg[idx];
    row_ptr[idx + 1] = incl;
    cursor[idx] = incl - d;
    inv_deg[idx] = (d > 0) ? (1.0f / (float)d) : 0.0f;
    if (idx == 0) row_ptr[0] = 0;
}

// plain scatter store (round-11 atomicExch experiment: 46 -> 67 us, WRITE_SIZE
// unchanged -- atomics serialize without reducing writeback amplification)
__global__ __launch_bounds__(256) void k_fill(const int* __restrict__ ei,
                                              int* __restrict__ cursor,
                                              int* __restrict__ csr_src) {
    const int e = blockIdx.x * 256 + threadIdx.x;
    if (e < EDGES) {
        const int d = ei[EDGES + e];
        if ((unsigned)d < NODES) {
            const int p = atomicAdd(&cursor[d], 1);
            csr_src[p] = ei[e];
        }
    }
}

// ws-too-small sentinel: absmax will read ~(1000 + ws_MB)
__global__ __launch_bounds__(256) void k_ws_stamp(unsigned short* __restrict__ outp, float v) {
    const int t = blockIdx.x * 256 + threadIdx.x;
    if (t < NGRAPH * 2) outp[t] = f2bf(v);
}

// ---------- mean aggregation: lane = 8 B (uint2); 8-deep gather batches ----------
// 8 uint2 loads in flight (4 KB/wave outstanding) at VGPR <= 64 so 8 waves/SIMD
// are retained (round-11 16-deep variant pushed VGPR past 64 and regressed).
// Writes bf16 agg at FIXED stride 128 shorts into `agg` (may alias GEMM output).
template <int CH>
__global__ __launch_bounds__(256) void k_agg(const unsigned short* __restrict__ h,   // N x CH
                                             const int* __restrict__ row_ptr,
                                             const int* __restrict__ csr_src,
                                             const float* __restrict__ inv_deg,
                                             unsigned short* __restrict__ agg) {     // N x 128
    constexpr int LPN = CH / 4;                 // uint2 lanes per node (32 or 16)
    constexpr int NPW = 64 / LPN;               // nodes per wave (2 or 4)
    const int wave = threadIdx.x >> 6;
    const int lane = threadIdx.x & 63;
    const int sub = lane / LPN;
    const int cl = lane & (LPN - 1);
    const int node = (blockIdx.x * 4 + wave) * NPW + sub;
    if (node >= NODES) return;
    const int e1 = row_ptr[node + 1];
    const uint2* hb = (const uint2*)h;
    float c0 = 0.f, c1 = 0.f, c2 = 0.f, c3 = 0.f;
    int e = row_ptr[node];
    for (; e + 7 < e1; e += 8) {
        uint2 u[8];
#pragma unroll
        for (int j = 0; j < 8; ++j)
            u[j] = hb[(size_t)csr_src[e + j] * LPN + cl];
#pragma unroll
        for (int j = 0; j < 8; ++j) {
            c0 += bflo(u[j].x); c1 += bfhi(u[j].x);
            c2 += bflo(u[j].y); c3 += bfhi(u[j].y);
        }
    }
    for (; e < e1; ++e) {
        const uint2 u = hb[(size_t)csr_src[e] * LPN + cl];
        c0 += bflo(u.x); c1 += bfhi(u.x);
        c2 += bflo(u.y); c3 += bfhi(u.y);
    }
    const float inv = inv_deg[node];
    uint2 o;
    o.x = f2bf(c0 * inv) | ((unsigned int)f2bf(c1 * inv) << 16);
    o.y = f2bf(c2 * inv) | ((unsigned int)f2bf(c3 * inv) << 16);
    ((uint2*)agg)[(size_t)node * 32 + cl] = o;
}

// ---------- MFMA SAGE GEMM: out = act(agg @ Wl + h @ Wr + b) ----------
// Block = 256 thr (4 waves), tile 64 rows x 128 cols. Wave w: rows
// m0 = blk*64 + (w&1)*32 (2 m-tiles), cols n0 = (w>>1)*64 (4 n-tiles) ->
// 8 MFMAs/step, B-frag reused 2x. Register double-buffer on A and B.
// Unified K-loop: steps 0..KC-1 = agg@Wl, KC..2KC-1 = h@Wr.
// mfma_f32_16x16x32_bf16 layouts (m89/m120-verified):
//   A-frag: lane holds A[m=lane&15][k=quad*8+j]; B-frag: B[k=quad*8+j][n=lane&15]
//   C/D: lane reg r holds D[row=quad*4+r][col=lane&15]
// agg stride 128; h stride CH. A reads and D writes cover the same rows, so agg
// may live in the output buffer. act: 0=none 1=relu 2=leaky(0.01)
template <int CH>
__global__ __launch_bounds__(256) void k_gemm(const unsigned short* __restrict__ agg, // N x 128
                                              const unsigned short* __restrict__ h,   // N x CH
                                              const unsigned short* __restrict__ Wt1, // [128][CH]
                                              const unsigned short* __restrict__ Wt2, // [128][CH]
                                              const unsigned short* __restrict__ bias,
                                              unsigned short* __restrict__ outp,      // N x 128
                                              int act) {
    const int wave = threadIdx.x >> 6;
    const int lane = threadIdx.x & 63;
    const int quad = lane >> 4;
    const int l16 = lane & 15;
    const int m0 = blockIdx.x * 64 + (wave & 1) * 32;
    const int n0 = (wave >> 1) * 64;
    int rowA0 = m0 + l16;
    int rowA1 = m0 + 16 + l16;
    if (rowA0 >= NODES) rowA0 = NODES - 1;   // clamped rows feed MFMA, never stored
    if (rowA1 >= NODES) rowA1 = NODES - 1;

    constexpr int KC = CH / 32;
    constexpr int NS = 2 * KC;

    auto loadA = [&](int s, int row) -> bf16x8 {
        const int half = (s >= KC) ? 1 : 0;
        const int kc = s - half * KC;
        const unsigned short* base = half ? h : agg;
        const int stride = half ? CH : 128;
        return *(const bf16x8*)(base + (size_t)row * stride + kc * 32 + quad * 8);
    };
    auto loadB = [&](int s, int nt) -> bf16x8 {
        const int half = (s >= KC) ? 1 : 0;
        const int kc = s - half * KC;
        const unsigned short* W = half ? Wt2 : Wt1;
        return *(const bf16x8*)(W + (size_t)(n0 + nt * 16 + l16) * CH + kc * 32 + quad * 8);
    };

    f32x4 acc[2][4] = {};
    bf16x8 a0 = loadA(0, rowA0);
    bf16x8 a1 = loadA(0, rowA1);
    bf16x8 b[4];
#pragma unroll
    for (int nt = 0; nt < 4; ++nt) b[nt] = loadB(0, nt);

#pragma unroll
    for (int s = 0; s < NS; ++s) {
        bf16x8 na0, na1, nb[4];
        if (s + 1 < NS) {                      // issue next step's loads first
            na0 = loadA(s + 1, rowA0);
            na1 = loadA(s + 1, rowA1);
#pragma unroll
            for (int nt = 0; nt < 4; ++nt) nb[nt] = loadB(s + 1, nt);
        }
#pragma unroll
        for (int nt = 0; nt < 4; ++nt) {
            acc[0][nt] = __builtin_amdgcn_mfma_f32_16x16x32_bf16(a0, b[nt], acc[0][nt], 0, 0, 0);
            acc[1][nt] = __builtin_amdgcn_mfma_f32_16x16x32_bf16(a1, b[nt], acc[1][nt], 0, 0, 0);
        }
        if (s + 1 < NS) {
            a0 = na0; a1 = na1;
#pragma unroll
            for (int nt = 0; nt < 4; ++nt) b[nt] = nb[nt];
        }
    }

#pragma unroll
    for (int nt = 0; nt < 4; ++nt) {
        const float bj = bf2f(bias[n0 + nt * 16 + l16]);
#pragma unroll
        for (int mt = 0; mt < 2; ++mt) {
#pragma unroll
            for (int r = 0; r < 4; ++r) {
                const int row = m0 + mt * 16 + quad * 4 + r;
                if (row < NODES) {
                    float v = acc[mt][nt][r] + bj;
                    if (act == 1) v = fmaxf(v, 0.f);
                    else if (act == 2) v = v > 0.f ? v : 0.01f * v;
                    outp[(size_t)row * 128 + n0 + nt * 16 + l16] = f2bf(v);
                }
            }
        }
    }
}

// ---------- segmented global mean pool (batch_idx sorted) ----------
// 512 threads = 4 substreams x 128 channels; block covers 128 nodes; substream
// sg scans nodes n0+4i+sg (sorted within stream), flushing at graph transitions.
__global__ __launch_bounds__(512) void k_pool(const unsigned short* __restrict__ h,
                                              const int* __restrict__ batch,
                                              float* __restrict__ gsum,
                                              float* __restrict__ gcnt) {
    const int c = threadIdx.x & 127;
    const int sg = threadIdx.x >> 7;            // 0..3
    const int n0 = blockIdx.x * 128;
    float s = 0.f;
    int cnt = 0, gprev = -1;
#pragma unroll 4
    for (int i = 0; i < 32; ++i) {
        const int n = n0 + i * 4 + sg;
        if (n >= NODES) break;
        int g = batch[n];
        if ((unsigned)g >= NGRAPH) g = (gprev < 0) ? 0 : gprev;
        if (g != gprev) {
            if (gprev >= 0) {
                atomicAdd(&gsum[(size_t)gprev * 128 + c], s);
                if (c == 0) atomicAdd(&gcnt[gprev], (float)cnt);
            }
            s = 0.f; cnt = 0; gprev = g;
        }
        s += bf2f(h[(size_t)n * 128 + c]);
        cnt++;
    }
    if (gprev >= 0) {
        atomicAdd(&gsum[(size_t)gprev * 128 + c], s);
        if (c == 0) atomicAdd(&gcnt[gprev], (float)cnt);
    }
}

// ---------- head: out = pooled @ head_W + head_b (dtype-adaptive store) ----------
__global__ __launch_bounds__(256) void k_head(const float* __restrict__ gsum,
                                              const float* __restrict__ gcnt,
                                              const unsigned short* __restrict__ wbuf,
                                              const void* __restrict__ xin,
                                              void* __restrict__ outp) {
    const int m = detect_mode((const unsigned int*)xin);   // before any divergent return
    const int t = blockIdx.x * 256 + threadIdx.x;
    if (t >= NGRAPH * 2) return;
    const int g = t >> 1, o = t & 1;
    const float inv = 1.0f / fmaxf(gcnt[g], 1.0f);
    float s = bf2f(wbuf[OFF_HB + o]);
    for (int c = 0; c < 128; ++c)
        s += gsum[(size_t)g * 128 + c] * inv * bf2f(wbuf[OFF_HW + c * 2 + o]);
    if (m) ((float*)outp)[t] = s;
    else ((unsigned short*)outp)[t] = f2bf(s);
}

extern "C" void kernel_launch(void* const* d_in, const int* in_sizes, int n_in,
                              void* d_out, int out_size, void* d_ws, size_t ws_size,
                              hipStream_t stream) {
    const void* x     = d_in[0];
    const int*  ei    = (const int*)d_in[1];
    const int*  batch = (const int*)d_in[2];

    // ---- workspace carve-up (~30.8 MB; ws_size measured 256 MB in round 8) ----
    char* p = (char*)d_ws;
    auto alloc = [&](size_t bytes) -> void* {
        void* r = (void*)p;
        p += (bytes + 255) & ~(size_t)255;
        return r;
    };
    unsigned short* hA   = (unsigned short*)alloc((size_t)NODES * 128 * 2);  // holds x (N x 64) first
    unsigned short* hB   = (unsigned short*)alloc((size_t)NODES * 128 * 2);
    unsigned short* wbuf = (unsigned short*)alloc((size_t)(WBUF_N + 14) * 2);
    int*   deg     = (int*)alloc((size_t)NODES * 4);
    int*   tmp     = (int*)alloc((size_t)NODES * 4);
    int*   row_ptr = (int*)alloc((size_t)(NODES + 1) * 4);
    int*   cursor  = (int*)alloc((size_t)NODES * 4);
    float* inv_deg = (float*)alloc((size_t)NODES * 4);
    int*   csr_src = (int*)alloc((size_t)EDGES * 4);
    int*   bsums   = (int*)alloc(64 * 4);
    float* gsum    = (float*)alloc((size_t)NGRAPH * 128 * 4);
    float* gcnt    = (float*)alloc((size_t)NGRAPH * 4);
    const size_t need = (size_t)(p - (char*)d_ws);
    (void)in_sizes; (void)n_in; (void)out_size;

    if (ws_size < need) {
        k_ws_stamp<<<4, 256, 0, stream>>>((unsigned short*)d_out,
                                          1000.0f + (float)(ws_size >> 20));
        return;
    }

    // setup: weight repack (mode sniffed block-locally), x convert + zero tail
    const int zeroBlocks = (ZERO_WORDS + 255) / 256;
    k_cvt_w<<<(WBUF_N + 255) / 256, 256, 0, stream>>>(x, d_in[3], d_in[4], d_in[5], d_in[6],
                                                      d_in[7], d_in[8], d_in[9], d_in[10], wbuf);
    k_cvt_x<<<CVT_BLOCKS + zeroBlocks, 256, 0, stream>>>(x, hA, deg, gsum, gcnt);

    // CSR build (by dst)
    const int nbScan = (NODES + 1023) / 1024;   // 49
    k_count<<<(EDGES + 255) / 256, 256, 0, stream>>>(ei, deg);
    k_scan_block<<<nbScan, 1024, 0, stream>>>(deg, tmp, bsums);
    k_scan_sums<<<1, 64, 0, stream>>>(bsums, nbScan);
    k_scan_fin<<<nbScan, 1024, 0, stream>>>(deg, tmp, bsums, row_ptr, cursor, inv_deg);
    k_fill<<<(EDGES + 255) / 256, 256, 0, stream>>>(ei, cursor, csr_src);

    const int gemmGrid = (NODES + 63) / 64;      // 782 (64 rows per block)

    // conv 0: 64 -> 128, ReLU. x in hA (N x 64); agg staged in hB (stride 128);
    // GEMM reads agg only from rows it itself overwrites -> no extra buffer.
    k_agg<64><<<(NODES + 15) / 16, 256, 0, stream>>>(hA, row_ptr, csr_src, inv_deg, hB);
    k_gemm<64><<<gemmGrid, 256, 0, stream>>>(hB, hA, wbuf + OFF_WL0T, wbuf + OFF_WR0T,
                                             wbuf + OFF_B0, hB, 1);

    // convs 1..11: 128 -> 128, ping-pong hB <-> hA (agg staged in nxt)
    unsigned short* cur = hB;
    unsigned short* nxt = hA;
    for (int i = 0; i < 11; ++i) {
        const int ci = i + 1;
        const int act = ((ci + 1) % 4 != 0) ? 1 : ((ci == 3 || ci == 7) ? 2 : 0);
        k_agg<128><<<(NODES + 7) / 8, 256, 0, stream>>>(cur, row_ptr, csr_src, inv_deg, nxt);
        k_gemm<128><<<gemmGrid, 256, 0, stream>>>(nxt, cur,
                                                  wbuf + OFF_WLT + (size_t)i * 128 * 128,
                                                  wbuf + OFF_WRT + (size_t)i * 128 * 128,
                                                  wbuf + OFF_B + (size_t)i * 128,
                                                  nxt, act);
        unsigned short* t = cur; cur = nxt; nxt = t;
    }

    // pool + head
    k_pool<<<(NODES + 127) / 128, 512, 0, stream>>>(cur, batch, gsum, gcnt);
    k_head<<<(NGRAPH * 2 + 255) / 256, 256, 0, stream>>>(gsum, gcnt, wbuf, x, d_out);
}